// Round 1
// baseline (3212.901 us; speedup 1.0000x reference)
//
#include <hip/hip_runtime.h>
#include <cstdint>
#include <cstddef>

#define D_MODEL 1024
#define N_HEADS 16
#define HEAD_DIM 64
#define SEQ 2048
#define BATCH 2

// ---------------------------------------------------------------------------
// GEMM1: X[4096,1024] @ Wqkv[1024,3072], epilogue scatters into Q/K/V buffers
// laid out [b*H+h][n][d]  (contiguous per-head rows for the attention kernel).
// Reference layout quirk: qkv reshape is (h, d, which) with `which` innermost:
//   which = c % 3, d = (c/3) % 64, h = c / 192
// ---------------------------------------------------------------------------
__global__ __launch_bounds__(256) void gemm_qkv_kernel(
    const float* __restrict__ X, const float* __restrict__ W,
    float* __restrict__ Q, float* __restrict__ Kb, float* __restrict__ Vb)
{
    const int Kd = D_MODEL;        // 1024
    const int Nn = 3 * D_MODEL;    // 3072

    __shared__ float As[16][64 + 1];
    __shared__ float Bs[16][64 + 1];

    const int tid = threadIdx.x;
    const int tx = tid & 15, ty = tid >> 4;
    const int row0 = blockIdx.y * 64;
    const int col0 = blockIdx.x * 64;

    const int am = tid >> 4;   // 0..15  (A: m index base)
    const int ak = tid & 15;   // 0..15  (A: k index)
    const int bk = tid >> 6;   // 0..3   (B: k index base)
    const int bn = tid & 63;   // 0..63  (B: n index)

    float acc[4][4] = {};

    for (int k0 = 0; k0 < Kd; k0 += 16) {
#pragma unroll
        for (int i = 0; i < 4; i++)
            As[ak][am + 16 * i] = X[(size_t)(row0 + am + 16 * i) * Kd + k0 + ak];
#pragma unroll
        for (int i = 0; i < 4; i++)
            Bs[bk + 4 * i][bn] = W[(size_t)(k0 + bk + 4 * i) * Nn + col0 + bn];
        __syncthreads();
#pragma unroll
        for (int kk = 0; kk < 16; kk++) {
            float a[4], b[4];
#pragma unroll
            for (int i = 0; i < 4; i++) a[i] = As[kk][ty + 16 * i];
#pragma unroll
            for (int j = 0; j < 4; j++) b[j] = Bs[kk][tx + 16 * j];
#pragma unroll
            for (int i = 0; i < 4; i++)
#pragma unroll
                for (int j = 0; j < 4; j++)
                    acc[i][j] = fmaf(a[i], b[j], acc[i][j]);
        }
        __syncthreads();
    }

#pragma unroll
    for (int i = 0; i < 4; i++) {
        const int r = row0 + ty + 16 * i;       // r = b*SEQ + n
        const int bb = r >> 11;                 // / 2048
        const int n  = r & (SEQ - 1);
#pragma unroll
        for (int j = 0; j < 4; j++) {
            const int c = col0 + tx + 16 * j;
            const int which = c % 3;
            const int d = (c / 3) & (HEAD_DIM - 1);
            const int h = c / (3 * HEAD_DIM);
            const size_t off =
                (((size_t)(bb * N_HEADS + h)) * SEQ + n) * HEAD_DIM + d;
            const float v = acc[i][j];
            if (which == 0)      Q[off]  = v;
            else if (which == 1) Kb[off] = v;
            else                 Vb[off] = v;
        }
    }
}

// ---------------------------------------------------------------------------
// GEMM2: O[4096,1024] @ Wproj[1024,1024] -> out[4096,1024]
// ---------------------------------------------------------------------------
__global__ __launch_bounds__(256) void gemm_proj_kernel(
    const float* __restrict__ A, const float* __restrict__ W,
    float* __restrict__ C)
{
    const int Kd = D_MODEL;
    const int Nn = D_MODEL;

    __shared__ float As[16][64 + 1];
    __shared__ float Bs[16][64 + 1];

    const int tid = threadIdx.x;
    const int tx = tid & 15, ty = tid >> 4;
    const int row0 = blockIdx.y * 64;
    const int col0 = blockIdx.x * 64;

    const int am = tid >> 4;
    const int ak = tid & 15;
    const int bk = tid >> 6;
    const int bn = tid & 63;

    float acc[4][4] = {};

    for (int k0 = 0; k0 < Kd; k0 += 16) {
#pragma unroll
        for (int i = 0; i < 4; i++)
            As[ak][am + 16 * i] = A[(size_t)(row0 + am + 16 * i) * Kd + k0 + ak];
#pragma unroll
        for (int i = 0; i < 4; i++)
            Bs[bk + 4 * i][bn] = W[(size_t)(k0 + bk + 4 * i) * Nn + col0 + bn];
        __syncthreads();
#pragma unroll
        for (int kk = 0; kk < 16; kk++) {
            float a[4], b[4];
#pragma unroll
            for (int i = 0; i < 4; i++) a[i] = As[kk][ty + 16 * i];
#pragma unroll
            for (int j = 0; j < 4; j++) b[j] = Bs[kk][tx + 16 * j];
#pragma unroll
            for (int i = 0; i < 4; i++)
#pragma unroll
                for (int j = 0; j < 4; j++)
                    acc[i][j] = fmaf(a[i], b[j], acc[i][j]);
        }
        __syncthreads();
    }

#pragma unroll
    for (int i = 0; i < 4; i++) {
        const int r = row0 + ty + 16 * i;
#pragma unroll
        for (int j = 0; j < 4; j++) {
            const int c = col0 + tx + 16 * j;
            C[(size_t)r * Nn + c] = acc[i][j];
        }
    }
}

// ---------------------------------------------------------------------------
// Attention: one block (256 thr) per (b,h,q) row. Causal: k in [0, q].
// Scores in LDS, block softmax, PV with coalesced V reads.
// O written in [b, n, h*64+d] layout (ready for proj GEMM).
// ---------------------------------------------------------------------------
__global__ __launch_bounds__(256) void attn_kernel(
    const float* __restrict__ Q, const float* __restrict__ K,
    const float* __restrict__ V, float* __restrict__ O)
{
    const int idx = blockIdx.x;
    const int q   = idx & (SEQ - 1);
    const int bh  = idx >> 11;            // 0..31  (b*16 + h)
    const int tid = threadIdx.x;

    __shared__ float sq[HEAD_DIM];
    __shared__ float sc[SEQ];
    __shared__ float red[256];

    const float* qrow = Q + ((size_t)bh * SEQ + q) * HEAD_DIM;
    if (tid < HEAD_DIM) sq[tid] = qrow[tid] * 0.125f;   // scale = 1/sqrt(64)
    __syncthreads();

    const int nk = q + 1;
    const float* kb = K + (size_t)bh * SEQ * HEAD_DIM;

    // scores
    for (int k = tid; k < nk; k += 256) {
        const float4* kr = (const float4*)(kb + (size_t)k * HEAD_DIM);
        float s = 0.0f;
#pragma unroll
        for (int i = 0; i < 16; i++) {
            float4 kv = kr[i];
            s = fmaf(sq[4 * i + 0], kv.x, s);
            s = fmaf(sq[4 * i + 1], kv.y, s);
            s = fmaf(sq[4 * i + 2], kv.z, s);
            s = fmaf(sq[4 * i + 3], kv.w, s);
        }
        sc[k] = s;
    }
    __syncthreads();

    // max reduce
    float m = -1e30f;
    for (int k = tid; k < nk; k += 256) m = fmaxf(m, sc[k]);
    red[tid] = m;
    __syncthreads();
    for (int s = 128; s > 0; s >>= 1) {
        if (tid < s) red[tid] = fmaxf(red[tid], red[tid + s]);
        __syncthreads();
    }
    m = red[0];
    __syncthreads();

    // exp + sum reduce
    float l = 0.0f;
    for (int k = tid; k < nk; k += 256) {
        float p = __expf(sc[k] - m);
        sc[k] = p;
        l += p;
    }
    red[tid] = l;
    __syncthreads();
    for (int s = 128; s > 0; s >>= 1) {
        if (tid < s) red[tid] += red[tid + s];
        __syncthreads();
    }
    const float inv = 1.0f / red[0];
    __syncthreads();   // before red[] reuse below

    // PV: thread = (g = tid>>6, d = tid&63); wave reads one V row (256B) / iter
    const int d = tid & 63, g = tid >> 6;
    const float* vb = V + (size_t)bh * SEQ * HEAD_DIM;
    float a0 = 0, a1 = 0, a2 = 0, a3 = 0;
    int k = g;
    for (; k + 12 < nk; k += 16) {
        a0 = fmaf(sc[k +  0], vb[(size_t)(k +  0) * HEAD_DIM + d], a0);
        a1 = fmaf(sc[k +  4], vb[(size_t)(k +  4) * HEAD_DIM + d], a1);
        a2 = fmaf(sc[k +  8], vb[(size_t)(k +  8) * HEAD_DIM + d], a2);
        a3 = fmaf(sc[k + 12], vb[(size_t)(k + 12) * HEAD_DIM + d], a3);
    }
    for (; k < nk; k += 4)
        a0 = fmaf(sc[k], vb[(size_t)k * HEAD_DIM + d], a0);
    red[tid] = a0 + a1 + a2 + a3;
    __syncthreads();

    if (tid < HEAD_DIM) {
        const float o =
            (red[tid] + red[tid + 64] + red[tid + 128] + red[tid + 192]) * inv;
        const int b = bh >> 4, h = bh & 15;
        O[((size_t)b * SEQ + q) * D_MODEL + h * HEAD_DIM + tid] = o;
    }
}

// ---------------------------------------------------------------------------
extern "C" void kernel_launch(void* const* d_in, const int* in_sizes, int n_in,
                              void* d_out, int out_size, void* d_ws, size_t ws_size,
                              hipStream_t stream) {
    const float* x      = (const float*)d_in[0];   // [2,2048,1024]
    const float* w_qkv  = (const float*)d_in[1];   // [1024,3072]
    const float* w_proj = (const float*)d_in[2];   // [1024,1024]
    float* out = (float*)d_out;                    // [2,2048,1024]

    const size_t per = (size_t)BATCH * N_HEADS * SEQ * HEAD_DIM;  // 4M floats
    float* Q = (float*)d_ws;
    float* K = Q + per;
    float* V = K + per;
    float* O = V + per;   // [2,2048,1024] = 4M floats; total ws 64 MB

    // qkv = x @ w_qkv, de-interleaved
    gemm_qkv_kernel<<<dim3(3 * D_MODEL / 64, BATCH * SEQ / 64), 256, 0, stream>>>(
        x, w_qkv, Q, K, V);

    // causal attention per (b,h,q)
    attn_kernel<<<dim3(BATCH * N_HEADS * SEQ), 256, 0, stream>>>(Q, K, V, O);

    // out = O @ w_proj
    gemm_proj_kernel<<<dim3(D_MODEL / 64, BATCH * SEQ / 64), 256, 0, stream>>>(
        O, w_proj, out);
}

// Round 2
// 767.204 us; speedup vs baseline: 4.1878x; 4.1878x over previous
//
#include <hip/hip_runtime.h>
#include <cstdint>
#include <cstddef>

#define D_MODEL 1024
#define N_HEADS 16
#define HEAD_DIM 64
#define SEQ 2048
#define BATCH 2

typedef __attribute__((ext_vector_type(8))) short bf16x8;
typedef __attribute__((ext_vector_type(4))) float f32x4;

__device__ inline unsigned short f2bf(float f) {
    union { float f; unsigned u; } v; v.f = f;
    unsigned r = v.u + 0x7fffu + ((v.u >> 16) & 1u);
    return (unsigned short)(r >> 16);
}

// ---------------------------------------------------------------------------
// GEMM1: X[4096,1024] @ Wqkv[1024,3072] (fp32 VALU), epilogue scatters bf16
// into Q[bh][n][d], K[bh][n][d], Vt[bh][d][n]  (bh = b*16+h).
// Reference layout quirk: which = c%3, d = (c/3)%64, h = c/192.
// ---------------------------------------------------------------------------
__global__ __launch_bounds__(256) void gemm_qkv_kernel(
    const float* __restrict__ X, const float* __restrict__ W,
    unsigned short* __restrict__ Q, unsigned short* __restrict__ Kb,
    unsigned short* __restrict__ Vt)
{
    const int Kd = D_MODEL;
    const int Nn = 3 * D_MODEL;

    __shared__ float As[16][64 + 1];
    __shared__ float Bs[16][64 + 1];

    const int tid = threadIdx.x;
    const int tx = tid & 15, ty = tid >> 4;
    const int row0 = blockIdx.y * 64;
    const int col0 = blockIdx.x * 64;

    const int am = tid >> 4;
    const int ak = tid & 15;
    const int bk = tid >> 6;
    const int bn = tid & 63;

    float acc[4][4] = {};

    for (int k0 = 0; k0 < Kd; k0 += 16) {
#pragma unroll
        for (int i = 0; i < 4; i++)
            As[ak][am + 16 * i] = X[(size_t)(row0 + am + 16 * i) * Kd + k0 + ak];
#pragma unroll
        for (int i = 0; i < 4; i++)
            Bs[bk + 4 * i][bn] = W[(size_t)(k0 + bk + 4 * i) * Nn + col0 + bn];
        __syncthreads();
#pragma unroll
        for (int kk = 0; kk < 16; kk++) {
            float a[4], b[4];
#pragma unroll
            for (int i = 0; i < 4; i++) a[i] = As[kk][ty + 16 * i];
#pragma unroll
            for (int j = 0; j < 4; j++) b[j] = Bs[kk][tx + 16 * j];
#pragma unroll
            for (int i = 0; i < 4; i++)
#pragma unroll
                for (int j = 0; j < 4; j++)
                    acc[i][j] = fmaf(a[i], b[j], acc[i][j]);
        }
        __syncthreads();
    }

#pragma unroll
    for (int i = 0; i < 4; i++) {
        const int r = row0 + ty + 16 * i;       // r = b*SEQ + n
        const int bb = r >> 11;
        const int n  = r & (SEQ - 1);
#pragma unroll
        for (int j = 0; j < 4; j++) {
            const int c = col0 + tx + 16 * j;
            const int which = c % 3;
            const int d = (c / 3) & (HEAD_DIM - 1);
            const int h = c / (3 * HEAD_DIM);
            const int bh = bb * N_HEADS + h;
            const unsigned short v = f2bf(acc[i][j]);
            if (which == 0)
                Q[((size_t)bh * SEQ + n) * HEAD_DIM + d] = v;
            else if (which == 1)
                Kb[((size_t)bh * SEQ + n) * HEAD_DIM + d] = v;
            else
                Vt[((size_t)bh * HEAD_DIM + d) * SEQ + n] = v;
        }
    }
}

// ---------------------------------------------------------------------------
// GEMM2: O[4096,1024] @ Wproj[1024,1024] -> out  (fp32 VALU, unchanged)
// ---------------------------------------------------------------------------
__global__ __launch_bounds__(256) void gemm_proj_kernel(
    const float* __restrict__ A, const float* __restrict__ W,
    float* __restrict__ C)
{
    const int Kd = D_MODEL;
    const int Nn = D_MODEL;

    __shared__ float As[16][64 + 1];
    __shared__ float Bs[16][64 + 1];

    const int tid = threadIdx.x;
    const int tx = tid & 15, ty = tid >> 4;
    const int row0 = blockIdx.y * 64;
    const int col0 = blockIdx.x * 64;

    const int am = tid >> 4;
    const int ak = tid & 15;
    const int bk = tid >> 6;
    const int bn = tid & 63;

    float acc[4][4] = {};

    for (int k0 = 0; k0 < Kd; k0 += 16) {
#pragma unroll
        for (int i = 0; i < 4; i++)
            As[ak][am + 16 * i] = A[(size_t)(row0 + am + 16 * i) * Kd + k0 + ak];
#pragma unroll
        for (int i = 0; i < 4; i++)
            Bs[bk + 4 * i][bn] = W[(size_t)(k0 + bk + 4 * i) * Nn + col0 + bn];
        __syncthreads();
#pragma unroll
        for (int kk = 0; kk < 16; kk++) {
            float a[4], b[4];
#pragma unroll
            for (int i = 0; i < 4; i++) a[i] = As[kk][ty + 16 * i];
#pragma unroll
            for (int j = 0; j < 4; j++) b[j] = Bs[kk][tx + 16 * j];
#pragma unroll
            for (int i = 0; i < 4; i++)
#pragma unroll
                for (int j = 0; j < 4; j++)
                    acc[i][j] = fmaf(a[i], b[j], acc[i][j]);
        }
        __syncthreads();
    }

#pragma unroll
    for (int i = 0; i < 4; i++) {
        const int r = row0 + ty + 16 * i;
#pragma unroll
        for (int j = 0; j < 4; j++) {
            const int c = col0 + tx + 16 * j;
            C[(size_t)r * Nn + c] = acc[i][j];
        }
    }
}

// ---------------------------------------------------------------------------
// Flash attention, bf16 MFMA. One block per (bh, 64-query tile); 4 waves,
// each wave owns 16 q-rows. LDS rows padded to 72 bf16 (144 B = 9*16 B) so
// ds_read_b128 fragment loads are 2-way-conflict-free.
//
// mfma_f32_16x16x32_bf16 layouts (verified m89/m91/m120):
//   A[m][k]: m = lane&15, k = (lane>>4)*8 + j          (8 contiguous k)
//   B[k][n]: n = lane&15, k = (lane>>4)*8 + j
//   D[m][n]: n = lane&15, m = (lane>>4)*4 + reg
// ---------------------------------------------------------------------------
#define LPAD 72   // padded row stride in bf16 elements

__global__ __launch_bounds__(256) void flash_attn_kernel(
    const unsigned short* __restrict__ Q,   // [32][2048][64] bf16
    const unsigned short* __restrict__ K,   // [32][2048][64] bf16
    const unsigned short* __restrict__ Vt,  // [32][64][2048] bf16 (transposed)
    float* __restrict__ O)                  // [2][2048][1024] fp32
{
    const int qt  = blockIdx.x;     // 0..31 query tile
    const int bh  = blockIdx.y;     // 0..31
    const int tid = threadIdx.x;
    const int w    = tid >> 6;      // wave 0..3
    const int lane = tid & 63;
    const int l15  = lane & 15;
    const int quad = lane >> 4;

    __shared__ unsigned short Qs[64 * LPAD];
    __shared__ unsigned short Ks[64 * LPAD];
    __shared__ unsigned short Vs[64 * LPAD];       // [d][kseq]
    __shared__ unsigned short Ps[4][16 * LPAD];    // per-wave P buffer

    // ---- stage Q tile (src contiguous 8 KB; dst rows padded to 9 uint4) ----
    {
        const uint4* src = (const uint4*)(Q + ((size_t)bh * SEQ + qt * 64) * HEAD_DIM);
        uint4* dst = (uint4*)Qs;
#pragma unroll
        for (int it = 0; it < 2; it++) {
            int idx = tid + it * 256;          // 0..511
            int row = idx >> 3, p = idx & 7;
            dst[row * 9 + p] = src[idx];
        }
    }

    const f32x4 zero4 = {0.f, 0.f, 0.f, 0.f};
    f32x4 o0 = zero4, o1 = zero4, o2 = zero4, o3 = zero4;
    float m_r[4], l_r[4];
#pragma unroll
    for (int r = 0; r < 4; r++) { m_r[r] = -1e30f; l_r[r] = 0.f; }

    for (int kt = 0; kt <= qt; kt++) {
        __syncthreads();   // previous-iteration readers done with Ks/Vs
        // ---- stage K tile ----
        {
            const uint4* src = (const uint4*)(K + ((size_t)bh * SEQ + kt * 64) * HEAD_DIM);
            uint4* dst = (uint4*)Ks;
#pragma unroll
            for (int it = 0; it < 2; it++) {
                int idx = tid + it * 256;
                int row = idx >> 3, p = idx & 7;
                dst[row * 9 + p] = src[idx];
            }
        }
        // ---- stage Vt tile: 64 rows (d), each 8 uint4 from strided src ----
        {
            const uint4* src = (const uint4*)Vt;   // rows of 256 uint4
            uint4* dst = (uint4*)Vs;
#pragma unroll
            for (int it = 0; it < 2; it++) {
                int idx = tid + it * 256;
                int d = idx >> 3, p = idx & 7;
                dst[d * 9 + p] = src[((size_t)bh * HEAD_DIM + d) * 256 + kt * 8 + p];
            }
        }
        __syncthreads();

        // ---- S = (Q K^T) for this wave's 16 rows ----
        f32x4 s[4];
#pragma unroll
        for (int ct = 0; ct < 4; ct++) s[ct] = zero4;
#pragma unroll
        for (int ks = 0; ks < 2; ks++) {
            bf16x8 qa = *(const bf16x8*)&Qs[(w * 16 + l15) * LPAD + quad * 8 + ks * 32];
#pragma unroll
            for (int ct = 0; ct < 4; ct++) {
                bf16x8 kb = *(const bf16x8*)&Ks[(ct * 16 + l15) * LPAD + quad * 8 + ks * 32];
                s[ct] = __builtin_amdgcn_mfma_f32_16x16x32_bf16(qa, kb, s[ct], 0, 0, 0);
            }
        }

        // ---- scale + causal mask + row max ----
        const int qg0 = qt * 64 + w * 16 + quad * 4;   // + r
        const bool diag = (kt == qt);
        float mt[4];
#pragma unroll
        for (int r = 0; r < 4; r++) mt[r] = -1e30f;
#pragma unroll
        for (int ct = 0; ct < 4; ct++) {
            const int kg = kt * 64 + ct * 16 + l15;
#pragma unroll
            for (int r = 0; r < 4; r++) {
                float v = s[ct][r] * 0.125f;
                if (diag && kg > qg0 + r) v = -1e30f;
                s[ct][r] = v;
                mt[r] = fmaxf(mt[r], v);
            }
        }
#pragma unroll
        for (int off = 1; off < 16; off <<= 1)
#pragma unroll
            for (int r = 0; r < 4; r++)
                mt[r] = fmaxf(mt[r], __shfl_xor(mt[r], off));

        float alpha[4];
#pragma unroll
        for (int r = 0; r < 4; r++) {
            float mn = fmaxf(m_r[r], mt[r]);
            alpha[r] = __expf(m_r[r] - mn);
            m_r[r] = mn;
        }

        // ---- p = exp(s - m); write P (bf16, row-major) to wave-private LDS ----
        float ls[4] = {0.f, 0.f, 0.f, 0.f};
#pragma unroll
        for (int ct = 0; ct < 4; ct++) {
#pragma unroll
            for (int r = 0; r < 4; r++) {
                float p = __expf(s[ct][r] - m_r[r]);
                ls[r] += p;
                Ps[w][(quad * 4 + r) * LPAD + ct * 16 + l15] = f2bf(p);
            }
        }
#pragma unroll
        for (int off = 1; off < 16; off <<= 1)
#pragma unroll
            for (int r = 0; r < 4; r++)
                ls[r] += __shfl_xor(ls[r], off);
#pragma unroll
        for (int r = 0; r < 4; r++)
            l_r[r] = l_r[r] * alpha[r] + ls[r];

        // ---- rescale O ----
#pragma unroll
        for (int r = 0; r < 4; r++) {
            o0[r] *= alpha[r]; o1[r] *= alpha[r];
            o2[r] *= alpha[r]; o3[r] *= alpha[r];
        }

        // ---- O += P V  (A-frag from wave-private Ps, B-frag from Vs) ----
#pragma unroll
        for (int ks = 0; ks < 2; ks++) {
            bf16x8 pa = *(const bf16x8*)&Ps[w][l15 * LPAD + quad * 8 + ks * 32];
            bf16x8 vb0 = *(const bf16x8*)&Vs[(0 * 16 + l15) * LPAD + quad * 8 + ks * 32];
            bf16x8 vb1 = *(const bf16x8*)&Vs[(1 * 16 + l15) * LPAD + quad * 8 + ks * 32];
            bf16x8 vb2 = *(const bf16x8*)&Vs[(2 * 16 + l15) * LPAD + quad * 8 + ks * 32];
            bf16x8 vb3 = *(const bf16x8*)&Vs[(3 * 16 + l15) * LPAD + quad * 8 + ks * 32];
            o0 = __builtin_amdgcn_mfma_f32_16x16x32_bf16(pa, vb0, o0, 0, 0, 0);
            o1 = __builtin_amdgcn_mfma_f32_16x16x32_bf16(pa, vb1, o1, 0, 0, 0);
            o2 = __builtin_amdgcn_mfma_f32_16x16x32_bf16(pa, vb2, o2, 0, 0, 0);
            o3 = __builtin_amdgcn_mfma_f32_16x16x32_bf16(pa, vb3, o3, 0, 0, 0);
        }
    }

    // ---- epilogue: O / l, write [b][n][h*64+d] fp32 ----
    const int b = bh >> 4, h = bh & 15;
#pragma unroll
    for (int r = 0; r < 4; r++) {
        const int q = qt * 64 + w * 16 + quad * 4 + r;
        const float inv = 1.0f / l_r[r];
        float* orow = O + ((size_t)b * SEQ + q) * D_MODEL + h * HEAD_DIM;
        orow[0 * 16 + l15] = o0[r] * inv;
        orow[1 * 16 + l15] = o1[r] * inv;
        orow[2 * 16 + l15] = o2[r] * inv;
        orow[3 * 16 + l15] = o3[r] * inv;
    }
}

// ---------------------------------------------------------------------------
extern "C" void kernel_launch(void* const* d_in, const int* in_sizes, int n_in,
                              void* d_out, int out_size, void* d_ws, size_t ws_size,
                              hipStream_t stream) {
    const float* x      = (const float*)d_in[0];
    const float* w_qkv  = (const float*)d_in[1];
    const float* w_proj = (const float*)d_in[2];
    float* out = (float*)d_out;

    const size_t per = (size_t)BATCH * N_HEADS * SEQ * HEAD_DIM;  // 4M elems
    unsigned short* Qb  = (unsigned short*)d_ws;   // bf16, 8 MB
    unsigned short* Kb  = Qb + per;                // 8 MB
    unsigned short* Vtb = Kb + per;                // 8 MB (transposed)
    float* O = (float*)(Vtb + per);                // fp32, 16 MB

    gemm_qkv_kernel<<<dim3(3 * D_MODEL / 64, BATCH * SEQ / 64), 256, 0, stream>>>(
        x, w_qkv, Qb, Kb, Vtb);

    flash_attn_kernel<<<dim3(SEQ / 64, BATCH * N_HEADS), 256, 0, stream>>>(
        Qb, Kb, Vtb, O);

    gemm_proj_kernel<<<dim3(D_MODEL / 64, BATCH * SEQ / 64), 256, 0, stream>>>(
        O, w_proj, out);
}

// Round 3
// 315.736 us; speedup vs baseline: 10.1759x; 2.4299x over previous
//
#include <hip/hip_runtime.h>
#include <cstdint>
#include <cstddef>

#define D_MODEL 1024
#define N_HEADS 16
#define HEAD_DIM 64
#define SEQ 2048
#define BATCH 2

typedef __attribute__((ext_vector_type(8))) short bf16x8;
typedef __attribute__((ext_vector_type(4))) float f32x4;

__device__ inline unsigned short f2bf(float f) {
    union { float f; unsigned u; } v; v.f = f;
    unsigned r = v.u + 0x7fffu + ((v.u >> 16) & 1u);
    return (unsigned short)(r >> 16);
}

// async global->LDS, 16 B per lane. l must be base + lane*16B (HW scatter rule).
__device__ __forceinline__ void gload_lds16(const unsigned short* g, unsigned short* l) {
    __builtin_amdgcn_global_load_lds(
        (const __attribute__((address_space(1))) unsigned int*)g,
        (__attribute__((address_space(3))) unsigned int*)l, 16, 0, 0);
}

// ---------------------------------------------------------------------------
// fp32 -> bf16 straight convert (x). 8 floats/thread.
// ---------------------------------------------------------------------------
__global__ __launch_bounds__(256) void convert_x_kernel(
    const float* __restrict__ X, unsigned short* __restrict__ Xb)
{
    const int idx = blockIdx.x * 256 + threadIdx.x;
    const float4* src = (const float4*)X;
    float4 v0 = src[idx * 2], v1 = src[idx * 2 + 1];
    union { unsigned short u[8]; uint4 v; } o;
    o.u[0] = f2bf(v0.x); o.u[1] = f2bf(v0.y); o.u[2] = f2bf(v0.z); o.u[3] = f2bf(v0.w);
    o.u[4] = f2bf(v1.x); o.u[5] = f2bf(v1.y); o.u[6] = f2bf(v1.z); o.u[7] = f2bf(v1.w);
    ((uint4*)Xb)[idx] = o.v;
}

// ---------------------------------------------------------------------------
// W[k][n] fp32 -> Wt[n][k] bf16, 32x32 LDS-tiled transpose.
// ---------------------------------------------------------------------------
__global__ __launch_bounds__(256) void convert_transpose_kernel(
    const float* __restrict__ W, unsigned short* __restrict__ Wt,
    int ncols /*n*/, int nrows /*k*/)
{
    __shared__ float t[32][33];
    const int c0 = blockIdx.x * 32, r0 = blockIdx.y * 32;
    const int a = threadIdx.x & 31, b = threadIdx.x >> 5;   // b: 0..7
#pragma unroll
    for (int i = 0; i < 32; i += 8)
        t[b + i][a] = W[(size_t)(r0 + b + i) * ncols + c0 + a];
    __syncthreads();
#pragma unroll
    for (int i = 0; i < 32; i += 8)
        Wt[(size_t)(c0 + b + i) * nrows + r0 + a] = f2bf(t[a][b + i]);
}

// ---------------------------------------------------------------------------
// bf16 MFMA GEMM core: C[128x128] tile, BK=64, A[m][k], B(=W^T)[n][k].
// LDS in fragment order: frag(mt,kt) of 16x32 at (mt*2+kt)*512, element for
// lane l at lane*8: A[mt*16+(l&15)][kt*32+(l>>4)*8 ..+8]. ds_read_b128 is
// conflict-free; global_load_lds dst = base + lane*16B exactly.
// Wave w (of 4): rows (w>>1)*64, cols (w&1)*64; 4x4 frags of 16x16.
// ---------------------------------------------------------------------------
#define GEMM_MFMA_BODY(A_, B_, Kdim)                                           \
    const int tid = threadIdx.x;                                               \
    const int w = tid >> 6, lane = tid & 63;                                   \
    const int l15 = lane & 15, quad = lane >> 4;                               \
    const int wr = w >> 1, wc = w & 1;                                         \
    const int row0 = blockIdx.y * 128, col0 = blockIdx.x * 128;                \
    __shared__ unsigned short As[8192];                                        \
    __shared__ unsigned short Bs[8192];                                        \
    const f32x4 zero4 = {0.f, 0.f, 0.f, 0.f};                                  \
    f32x4 acc[4][4];                                                           \
    _Pragma("unroll") for (int i = 0; i < 4; i++)                              \
        _Pragma("unroll") for (int j = 0; j < 4; j++) acc[i][j] = zero4;       \
    for (int k0 = 0; k0 < (Kdim); k0 += 64) {                                  \
        __syncthreads();                                                       \
        _Pragma("unroll") for (int f = 0; f < 4; f++) {                        \
            const int fa = w * 4 + f;                                          \
            const int mt = fa >> 1, kt = fa & 1;                               \
            const int kcol = k0 + kt * 32 + quad * 8;                          \
            gload_lds16((A_) + (size_t)(row0 + mt * 16 + l15) * (Kdim) + kcol, \
                        &As[fa * 512 + lane * 8]);                             \
            gload_lds16((B_) + (size_t)(col0 + mt * 16 + l15) * (Kdim) + kcol, \
                        &Bs[fa * 512 + lane * 8]);                             \
        }                                                                      \
        __syncthreads();                                                       \
        _Pragma("unroll") for (int kt = 0; kt < 2; kt++) {                     \
            bf16x8 af[4], bf[4];                                               \
            _Pragma("unroll") for (int i = 0; i < 4; i++)                      \
                af[i] = *(const bf16x8*)&As[((wr * 4 + i) * 2 + kt) * 512 + lane * 8]; \
            _Pragma("unroll") for (int j = 0; j < 4; j++)                      \
                bf[j] = *(const bf16x8*)&Bs[((wc * 4 + j) * 2 + kt) * 512 + lane * 8]; \
            _Pragma("unroll") for (int i = 0; i < 4; i++)                      \
                _Pragma("unroll") for (int j = 0; j < 4; j++)                  \
                    acc[i][j] = __builtin_amdgcn_mfma_f32_16x16x32_bf16(       \
                        af[i], bf[j], acc[i][j], 0, 0, 0);                     \
        }                                                                      \
    }

// GEMM1: Xb[4096][1024] @ Wqt[3072][1024]^T, scatter epilogue -> Q/K/Vt bf16.
// which = c%3, d = (c/3)%64, h = c/192.
__global__ __launch_bounds__(256) void gemm_qkv_mfma(
    const unsigned short* __restrict__ A, const unsigned short* __restrict__ B,
    unsigned short* __restrict__ Q, unsigned short* __restrict__ Kq,
    unsigned short* __restrict__ Vt)
{
    GEMM_MFMA_BODY(A, B, D_MODEL)
#pragma unroll
    for (int i = 0; i < 4; i++) {
#pragma unroll
        for (int r = 0; r < 4; r++) {
            const int row = row0 + wr * 64 + i * 16 + quad * 4 + r;
            const int bb = row >> 11, n = row & (SEQ - 1);
#pragma unroll
            for (int j = 0; j < 4; j++) {
                const int c = col0 + wc * 64 + j * 16 + l15;
                const int which = c % 3;
                const int dd = (c / 3) & (HEAD_DIM - 1);
                const int h = c / (3 * HEAD_DIM);
                const int bh = bb * N_HEADS + h;
                const unsigned short v = f2bf(acc[i][j][r]);
                if (which == 0)
                    Q[((size_t)bh * SEQ + n) * HEAD_DIM + dd] = v;
                else if (which == 1)
                    Kq[((size_t)bh * SEQ + n) * HEAD_DIM + dd] = v;
                else
                    Vt[((size_t)bh * HEAD_DIM + dd) * SEQ + n] = v;
            }
        }
    }
}

// GEMM2: Ob[4096][1024] @ Wpt[1024][1024]^T -> out fp32.
__global__ __launch_bounds__(256) void gemm_proj_mfma(
    const unsigned short* __restrict__ A, const unsigned short* __restrict__ B,
    float* __restrict__ C)
{
    GEMM_MFMA_BODY(A, B, D_MODEL)
#pragma unroll
    for (int i = 0; i < 4; i++) {
#pragma unroll
        for (int r = 0; r < 4; r++) {
            const int row = row0 + wr * 64 + i * 16 + quad * 4 + r;
#pragma unroll
            for (int j = 0; j < 4; j++) {
                const int c = col0 + wc * 64 + j * 16 + l15;
                C[(size_t)row * D_MODEL + c] = acc[i][j][r];
            }
        }
    }
}

// ---------------------------------------------------------------------------
// Flash attention (unchanged from R2 except O written as bf16).
// ---------------------------------------------------------------------------
#define LPAD 72

__global__ __launch_bounds__(256) void flash_attn_kernel(
    const unsigned short* __restrict__ Q,
    const unsigned short* __restrict__ K,
    const unsigned short* __restrict__ Vt,
    unsigned short* __restrict__ O)      // [2][2048][1024] bf16
{
    const int qt  = blockIdx.x;
    const int bh  = blockIdx.y;
    const int tid = threadIdx.x;
    const int w    = tid >> 6;
    const int lane = tid & 63;
    const int l15  = lane & 15;
    const int quad = lane >> 4;

    __shared__ unsigned short Qs[64 * LPAD];
    __shared__ unsigned short Ks[64 * LPAD];
    __shared__ unsigned short Vs[64 * LPAD];
    __shared__ unsigned short Ps[4][16 * LPAD];

    {
        const uint4* src = (const uint4*)(Q + ((size_t)bh * SEQ + qt * 64) * HEAD_DIM);
        uint4* dst = (uint4*)Qs;
#pragma unroll
        for (int it = 0; it < 2; it++) {
            int idx = tid + it * 256;
            int row = idx >> 3, p = idx & 7;
            dst[row * 9 + p] = src[idx];
        }
    }

    const f32x4 zero4 = {0.f, 0.f, 0.f, 0.f};
    f32x4 o0 = zero4, o1 = zero4, o2 = zero4, o3 = zero4;
    float m_r[4], l_r[4];
#pragma unroll
    for (int r = 0; r < 4; r++) { m_r[r] = -1e30f; l_r[r] = 0.f; }

    for (int kt = 0; kt <= qt; kt++) {
        __syncthreads();
        {
            const uint4* src = (const uint4*)(K + ((size_t)bh * SEQ + kt * 64) * HEAD_DIM);
            uint4* dst = (uint4*)Ks;
#pragma unroll
            for (int it = 0; it < 2; it++) {
                int idx = tid + it * 256;
                int row = idx >> 3, p = idx & 7;
                dst[row * 9 + p] = src[idx];
            }
        }
        {
            const uint4* src = (const uint4*)Vt;
            uint4* dst = (uint4*)Vs;
#pragma unroll
            for (int it = 0; it < 2; it++) {
                int idx = tid + it * 256;
                int d = idx >> 3, p = idx & 7;
                dst[d * 9 + p] = src[((size_t)bh * HEAD_DIM + d) * 256 + kt * 8 + p];
            }
        }
        __syncthreads();

        f32x4 s[4];
#pragma unroll
        for (int ct = 0; ct < 4; ct++) s[ct] = zero4;
#pragma unroll
        for (int ks = 0; ks < 2; ks++) {
            bf16x8 qa = *(const bf16x8*)&Qs[(w * 16 + l15) * LPAD + quad * 8 + ks * 32];
#pragma unroll
            for (int ct = 0; ct < 4; ct++) {
                bf16x8 kb = *(const bf16x8*)&Ks[(ct * 16 + l15) * LPAD + quad * 8 + ks * 32];
                s[ct] = __builtin_amdgcn_mfma_f32_16x16x32_bf16(qa, kb, s[ct], 0, 0, 0);
            }
        }

        const int qg0 = qt * 64 + w * 16 + quad * 4;
        const bool diag = (kt == qt);
        float mt[4];
#pragma unroll
        for (int r = 0; r < 4; r++) mt[r] = -1e30f;
#pragma unroll
        for (int ct = 0; ct < 4; ct++) {
            const int kg = kt * 64 + ct * 16 + l15;
#pragma unroll
            for (int r = 0; r < 4; r++) {
                float v = s[ct][r] * 0.125f;
                if (diag && kg > qg0 + r) v = -1e30f;
                s[ct][r] = v;
                mt[r] = fmaxf(mt[r], v);
            }
        }
#pragma unroll
        for (int off = 1; off < 16; off <<= 1)
#pragma unroll
            for (int r = 0; r < 4; r++)
                mt[r] = fmaxf(mt[r], __shfl_xor(mt[r], off));

        float alpha[4];
#pragma unroll
        for (int r = 0; r < 4; r++) {
            float mn = fmaxf(m_r[r], mt[r]);
            alpha[r] = __expf(m_r[r] - mn);
            m_r[r] = mn;
        }

        float ls[4] = {0.f, 0.f, 0.f, 0.f};
#pragma unroll
        for (int ct = 0; ct < 4; ct++) {
#pragma unroll
            for (int r = 0; r < 4; r++) {
                float p = __expf(s[ct][r] - m_r[r]);
                ls[r] += p;
                Ps[w][(quad * 4 + r) * LPAD + ct * 16 + l15] = f2bf(p);
            }
        }
#pragma unroll
        for (int off = 1; off < 16; off <<= 1)
#pragma unroll
            for (int r = 0; r < 4; r++)
                ls[r] += __shfl_xor(ls[r], off);
#pragma unroll
        for (int r = 0; r < 4; r++)
            l_r[r] = l_r[r] * alpha[r] + ls[r];

#pragma unroll
        for (int r = 0; r < 4; r++) {
            o0[r] *= alpha[r]; o1[r] *= alpha[r];
            o2[r] *= alpha[r]; o3[r] *= alpha[r];
        }

#pragma unroll
        for (int ks = 0; ks < 2; ks++) {
            bf16x8 pa = *(const bf16x8*)&Ps[w][l15 * LPAD + quad * 8 + ks * 32];
            bf16x8 vb0 = *(const bf16x8*)&Vs[(0 * 16 + l15) * LPAD + quad * 8 + ks * 32];
            bf16x8 vb1 = *(const bf16x8*)&Vs[(1 * 16 + l15) * LPAD + quad * 8 + ks * 32];
            bf16x8 vb2 = *(const bf16x8*)&Vs[(2 * 16 + l15) * LPAD + quad * 8 + ks * 32];
            bf16x8 vb3 = *(const bf16x8*)&Vs[(3 * 16 + l15) * LPAD + quad * 8 + ks * 32];
            o0 = __builtin_amdgcn_mfma_f32_16x16x32_bf16(pa, vb0, o0, 0, 0, 0);
            o1 = __builtin_amdgcn_mfma_f32_16x16x32_bf16(pa, vb1, o1, 0, 0, 0);
            o2 = __builtin_amdgcn_mfma_f32_16x16x32_bf16(pa, vb2, o2, 0, 0, 0);
            o3 = __builtin_amdgcn_mfma_f32_16x16x32_bf16(pa, vb3, o3, 0, 0, 0);
        }
    }

    const int b = bh >> 4, h = bh & 15;
#pragma unroll
    for (int r = 0; r < 4; r++) {
        const int q = qt * 64 + w * 16 + quad * 4 + r;
        const float inv = 1.0f / l_r[r];
        unsigned short* orow = O + ((size_t)b * SEQ + q) * D_MODEL + h * HEAD_DIM;
        orow[0 * 16 + l15] = f2bf(o0[r] * inv);
        orow[1 * 16 + l15] = f2bf(o1[r] * inv);
        orow[2 * 16 + l15] = f2bf(o2[r] * inv);
        orow[3 * 16 + l15] = f2bf(o3[r] * inv);
    }
}

// ---------------------------------------------------------------------------
extern "C" void kernel_launch(void* const* d_in, const int* in_sizes, int n_in,
                              void* d_out, int out_size, void* d_ws, size_t ws_size,
                              hipStream_t stream) {
    const float* x      = (const float*)d_in[0];
    const float* w_qkv  = (const float*)d_in[1];
    const float* w_proj = (const float*)d_in[2];
    float* out = (float*)d_out;

    unsigned short* Xb  = (unsigned short*)d_ws;          // 4M
    unsigned short* Wqt = Xb  + (size_t)4 * 1024 * 1024;  // 3M [3072][1024]
    unsigned short* Wpt = Wqt + (size_t)3 * 1024 * 1024;  // 1M [1024][1024]
    unsigned short* Qb  = Wpt + (size_t)1 * 1024 * 1024;  // 4M
    unsigned short* Kb  = Qb  + (size_t)4 * 1024 * 1024;  // 4M
    unsigned short* Vtb = Kb  + (size_t)4 * 1024 * 1024;  // 4M
    unsigned short* Ob  = Vtb + (size_t)4 * 1024 * 1024;  // 4M  (48 MB total)

    convert_x_kernel<<<dim3(2048), 256, 0, stream>>>(x, Xb);
    convert_transpose_kernel<<<dim3(3072 / 32, 1024 / 32), 256, 0, stream>>>(
        w_qkv, Wqt, 3 * D_MODEL, D_MODEL);
    convert_transpose_kernel<<<dim3(1024 / 32, 1024 / 32), 256, 0, stream>>>(
        w_proj, Wpt, D_MODEL, D_MODEL);

    gemm_qkv_mfma<<<dim3(3 * D_MODEL / 128, BATCH * SEQ / 128), 256, 0, stream>>>(
        Xb, Wqt, Qb, Kb, Vtb);

    flash_attn_kernel<<<dim3(SEQ / 64, BATCH * N_HEADS), 256, 0, stream>>>(
        Qb, Kb, Vtb, Ob);

    gemm_proj_mfma<<<dim3(D_MODEL / 128, BATCH * SEQ / 128), 256, 0, stream>>>(
        Ob, Wpt, out);
}

// Round 4
// 244.604 us; speedup vs baseline: 13.1351x; 1.2908x over previous
//
#include <hip/hip_runtime.h>
#include <cstdint>
#include <cstddef>

#define D_MODEL 1024
#define N_HEADS 16
#define HEAD_DIM 64
#define SEQ 2048
#define BATCH 2

typedef __attribute__((ext_vector_type(8))) short bf16x8;
typedef __attribute__((ext_vector_type(4))) float f32x4;

__device__ inline unsigned short f2bf(float f) {
    union { float f; unsigned u; } v; v.f = f;
    unsigned r = v.u + 0x7fffu + ((v.u >> 16) & 1u);
    return (unsigned short)(r >> 16);
}

// async global->LDS, 16 B per lane; LDS dst must be wave-base + lane*16.
__device__ __forceinline__ void gload_lds16(const unsigned short* g, unsigned short* l) {
    __builtin_amdgcn_global_load_lds(
        (const __attribute__((address_space(1))) unsigned int*)g,
        (__attribute__((address_space(3))) unsigned int*)l, 16, 0, 0);
}

// ---------------------------------------------------------------------------
// fp32 -> bf16 straight convert (x). 8 floats/thread.
// ---------------------------------------------------------------------------
__global__ __launch_bounds__(256) void convert_x_kernel(
    const float* __restrict__ X, unsigned short* __restrict__ Xb)
{
    const int idx = blockIdx.x * 256 + threadIdx.x;
    const float4* src = (const float4*)X;
    float4 v0 = src[idx * 2], v1 = src[idx * 2 + 1];
    union { unsigned short u[8]; uint4 v; } o;
    o.u[0] = f2bf(v0.x); o.u[1] = f2bf(v0.y); o.u[2] = f2bf(v0.z); o.u[3] = f2bf(v0.w);
    o.u[4] = f2bf(v1.x); o.u[5] = f2bf(v1.y); o.u[6] = f2bf(v1.z); o.u[7] = f2bf(v1.w);
    ((uint4*)Xb)[idx] = o.v;
}

// ---------------------------------------------------------------------------
// W[k][n] fp32 -> Wt[n][k] bf16, 32x32 LDS-tiled transpose.
// ---------------------------------------------------------------------------
__global__ __launch_bounds__(256) void convert_transpose_kernel(
    const float* __restrict__ W, unsigned short* __restrict__ Wt,
    int ncols, int nrows)
{
    __shared__ float t[32][33];
    const int c0 = blockIdx.x * 32, r0 = blockIdx.y * 32;
    const int a = threadIdx.x & 31, b = threadIdx.x >> 5;
#pragma unroll
    for (int i = 0; i < 32; i += 8)
        t[b + i][a] = W[(size_t)(r0 + b + i) * ncols + c0 + a];
    __syncthreads();
#pragma unroll
    for (int i = 0; i < 32; i += 8)
        Wt[(size_t)(c0 + b + i) * nrows + r0 + a] = f2bf(t[a][b + i]);
}

// ---------------------------------------------------------------------------
// bf16 MFMA GEMM core (unchanged from R3): 128x128 tile, BK=64, frag-order LDS.
// ---------------------------------------------------------------------------
#define GEMM_MFMA_BODY(A_, B_, Kdim)                                           \
    const int tid = threadIdx.x;                                               \
    const int w = tid >> 6, lane = tid & 63;                                   \
    const int l15 = lane & 15, quad = lane >> 4;                               \
    const int wr = w >> 1, wc = w & 1;                                         \
    const int row0 = blockIdx.y * 128, col0 = blockIdx.x * 128;                \
    __shared__ unsigned short As[8192];                                        \
    __shared__ unsigned short Bs[8192];                                        \
    const f32x4 zero4 = {0.f, 0.f, 0.f, 0.f};                                  \
    f32x4 acc[4][4];                                                           \
    _Pragma("unroll") for (int i = 0; i < 4; i++)                              \
        _Pragma("unroll") for (int j = 0; j < 4; j++) acc[i][j] = zero4;       \
    for (int k0 = 0; k0 < (Kdim); k0 += 64) {                                  \
        __syncthreads();                                                       \
        _Pragma("unroll") for (int f = 0; f < 4; f++) {                        \
            const int fa = w * 4 + f;                                          \
            const int mt = fa >> 1, kt = fa & 1;                               \
            const int kcol = k0 + kt * 32 + quad * 8;                          \
            gload_lds16((A_) + (size_t)(row0 + mt * 16 + l15) * (Kdim) + kcol, \
                        &As[fa * 512 + lane * 8]);                             \
            gload_lds16((B_) + (size_t)(col0 + mt * 16 + l15) * (Kdim) + kcol, \
                        &Bs[fa * 512 + lane * 8]);                             \
        }                                                                      \
        __syncthreads();                                                       \
        _Pragma("unroll") for (int kt = 0; kt < 2; kt++) {                     \
            bf16x8 af[4], bf[4];                                               \
            _Pragma("unroll") for (int i = 0; i < 4; i++)                      \
                af[i] = *(const bf16x8*)&As[((wr * 4 + i) * 2 + kt) * 512 + lane * 8]; \
            _Pragma("unroll") for (int j = 0; j < 4; j++)                      \
                bf[j] = *(const bf16x8*)&Bs[((wc * 4 + j) * 2 + kt) * 512 + lane * 8]; \
            _Pragma("unroll") for (int i = 0; i < 4; i++)                      \
                _Pragma("unroll") for (int j = 0; j < 4; j++)                  \
                    acc[i][j] = __builtin_amdgcn_mfma_f32_16x16x32_bf16(       \
                        af[i], bf[j], acc[i][j], 0, 0, 0);                     \
        }                                                                      \
    }

__global__ __launch_bounds__(256) void gemm_qkv_mfma(
    const unsigned short* __restrict__ A, const unsigned short* __restrict__ B,
    unsigned short* __restrict__ Q, unsigned short* __restrict__ Kq,
    unsigned short* __restrict__ Vt)
{
    GEMM_MFMA_BODY(A, B, D_MODEL)
#pragma unroll
    for (int i = 0; i < 4; i++) {
#pragma unroll
        for (int r = 0; r < 4; r++) {
            const int row = row0 + wr * 64 + i * 16 + quad * 4 + r;
            const int bb = row >> 11, n = row & (SEQ - 1);
#pragma unroll
            for (int j = 0; j < 4; j++) {
                const int c = col0 + wc * 64 + j * 16 + l15;
                const int which = c % 3;
                const int dd = (c / 3) & (HEAD_DIM - 1);
                const int h = c / (3 * HEAD_DIM);
                const int bh = bb * N_HEADS + h;
                const unsigned short v = f2bf(acc[i][j][r]);
                if (which == 0)
                    Q[((size_t)bh * SEQ + n) * HEAD_DIM + dd] = v;
                else if (which == 1)
                    Kq[((size_t)bh * SEQ + n) * HEAD_DIM + dd] = v;
                else
                    Vt[((size_t)bh * HEAD_DIM + dd) * SEQ + n] = v;
            }
        }
    }
}

__global__ __launch_bounds__(256) void gemm_proj_mfma(
    const unsigned short* __restrict__ A, const unsigned short* __restrict__ B,
    float* __restrict__ C)
{
    GEMM_MFMA_BODY(A, B, D_MODEL)
#pragma unroll
    for (int i = 0; i < 4; i++) {
#pragma unroll
        for (int r = 0; r < 4; r++) {
            const int row = row0 + wr * 64 + i * 16 + quad * 4 + r;
#pragma unroll
            for (int j = 0; j < 4; j++) {
                const int c = col0 + wc * 64 + j * 16 + l15;
                C[(size_t)row * D_MODEL + c] = acc[i][j][r];
            }
        }
    }
}

// ---------------------------------------------------------------------------
// Flash attention v2: S^T trick + register Q + async double-buffered K/V.
//   S^T = K·Q^T :  A-frag = K (m=key),  B-frag = Q (n=query)
//   D[m=key=quad*4+r][n=query=l15]  -> softmax reduce: 4 regs + shfl 16/32
//   P packed as b64 per ct into Ps[query][key]; PV reads A-frag b128.
//   O (PV out): D[m=query=quad*4+r][n=d=l15]; alpha crossed via __shfl.
// LDS: Ks 2x8K + Vs 2x8K + Ps 9216 B = 41 KB -> 3 blocks/CU.
// ---------------------------------------------------------------------------
#define PSTR 72   // Ps row stride (bf16): 144 B = 9*16 B

__global__ __launch_bounds__(256) void flash_attn_kernel(
    const unsigned short* __restrict__ Q,   // [32][2048][64]
    const unsigned short* __restrict__ K,   // [32][2048][64]
    const unsigned short* __restrict__ Vt,  // [32][64][2048]
    unsigned short* __restrict__ O)         // [2][2048][1024] bf16
{
    const int idx = blockIdx.x;          // 0..1023
    const int bh = idx & 31;
    const int qt2 = idx >> 5;            // 0..31
    // balanced mapping: CU-stride groups {lo, 31-lo, lo+8, 23-lo} sum to 62
    const int hi = qt2 >> 3, lo = qt2 & 7;
    const int qt = (hi == 0) ? lo : (hi == 1) ? 31 - lo : (hi == 2) ? lo + 8 : 23 - lo;

    const int tid = threadIdx.x;
    const int w = tid >> 6, lane = tid & 63;
    const int l15 = lane & 15, quad = lane >> 4;

    __shared__ unsigned short Ks[2][4096];
    __shared__ unsigned short Vs[2][4096];
    __shared__ unsigned short Ps[4][16 * PSTR];

    // Q fragments in registers: wave w owns queries qt*64 + w*16 + {0..15}
    bf16x8 qf[2];
    {
        const unsigned short* qrow =
            Q + ((size_t)bh * SEQ + qt * 64 + w * 16 + l15) * HEAD_DIM;
        qf[0] = *(const bf16x8*)(qrow + quad * 8);
        qf[1] = *(const bf16x8*)(qrow + 32 + quad * 8);
    }

    const f32x4 zero4 = {0.f, 0.f, 0.f, 0.f};
    f32x4 o_acc[4] = {zero4, zero4, zero4, zero4};   // [dt]; rows=query, cols=d
    float m_i = -1e30f, l_i = 0.f;                    // per lane: query w*16+l15

    // stage k-tile `kt_t` into buffer `bf`: wave w loads frags w*2, w*2+1
    auto stage = [&](int bf, int kt_t) {
        const int key0 = kt_t * 64;
#pragma unroll
        for (int i = 0; i < 2; i++) {
            const int f = w * 2 + i;
            const int ct = f >> 1, kh = f & 1;
            gload_lds16(K + ((size_t)bh * SEQ + key0 + ct * 16 + l15) * HEAD_DIM
                          + kh * 32 + quad * 8,
                        &Ks[bf][f * 512 + lane * 8]);
            gload_lds16(Vt + ((size_t)bh * HEAD_DIM + ct * 16 + l15) * SEQ
                           + key0 + kh * 32 + quad * 8,
                        &Vs[bf][f * 512 + lane * 8]);
        }
    };

    stage(0, 0);
    int buf = 0;

    const int qg = qt * 64 + w * 16 + l15;   // this lane's query (for mask/softmax)

    for (int kt = 0; kt <= qt; kt++) {
        __syncthreads();                 // drains vmcnt -> buf is ready
        if (kt < qt) stage(buf ^ 1, kt + 1);   // async prefetch, lands by next barrier

        // ---- S^T = K Q^T : st[ct], rows=key, cols=query ----
        f32x4 st[4] = {zero4, zero4, zero4, zero4};
#pragma unroll
        for (int kh = 0; kh < 2; kh++) {
#pragma unroll
            for (int ct = 0; ct < 4; ct++) {
                bf16x8 kf = *(const bf16x8*)&Ks[buf][(ct * 2 + kh) * 512 + lane * 8];
                st[ct] = __builtin_amdgcn_mfma_f32_16x16x32_bf16(kf, qf[kh], st[ct], 0, 0, 0);
            }
        }

        // ---- scale + causal mask + per-query max (in-reg + 2 shuffles) ----
        const bool diag = (kt == qt);
        float mt = -1e30f;
#pragma unroll
        for (int ct = 0; ct < 4; ct++) {
#pragma unroll
            for (int r = 0; r < 4; r++) {
                float v = st[ct][r] * 0.125f;
                const int kg = kt * 64 + ct * 16 + quad * 4 + r;
                if (diag && kg > qg) v = -1e30f;
                st[ct][r] = v;
                mt = fmaxf(mt, v);
            }
        }
        mt = fmaxf(mt, __shfl_xor(mt, 16));
        mt = fmaxf(mt, __shfl_xor(mt, 32));

        const float mn = fmaxf(m_i, mt);
        const float alpha = __expf(m_i - mn);
        m_i = mn;

        // ---- p = exp(s-m), pack 4 keys -> one b64 LDS write per ct ----
        float ls = 0.f;
#pragma unroll
        for (int ct = 0; ct < 4; ct++) {
            union { unsigned short u[4]; uint2 v; } pk;
#pragma unroll
            for (int r = 0; r < 4; r++) {
                float p = __expf(st[ct][r] - mn);
                ls += p;
                pk.u[r] = f2bf(p);
            }
            *(uint2*)&Ps[w][l15 * PSTR + ct * 16 + quad * 4] = pk.v;
        }
        ls += __shfl_xor(ls, 16);
        ls += __shfl_xor(ls, 32);
        l_i = l_i * alpha + ls;

        // ---- rescale O: alpha per O-row (query quad*4+r) via shfl ----
        float ar[4];
#pragma unroll
        for (int r = 0; r < 4; r++)
            ar[r] = __shfl(alpha, (lane & 48) | (quad * 4 + r));
#pragma unroll
        for (int dt = 0; dt < 4; dt++)
#pragma unroll
            for (int r = 0; r < 4; r++)
                o_acc[dt][r] *= ar[r];

        // ---- O += P V ----
#pragma unroll
        for (int kh = 0; kh < 2; kh++) {
            bf16x8 pa = *(const bf16x8*)&Ps[w][l15 * PSTR + kh * 32 + quad * 8];
#pragma unroll
            for (int dt = 0; dt < 4; dt++) {
                bf16x8 vf = *(const bf16x8*)&Vs[buf][(dt * 2 + kh) * 512 + lane * 8];
                o_acc[dt] = __builtin_amdgcn_mfma_f32_16x16x32_bf16(pa, vf, o_acc[dt], 0, 0, 0);
            }
        }
        buf ^= 1;
    }

    // ---- epilogue: normalize by l (per query, crossed via shfl), store bf16 ----
    const float linv = 1.0f / l_i;
    float lr[4];
#pragma unroll
    for (int r = 0; r < 4; r++)
        lr[r] = __shfl(linv, (lane & 48) | (quad * 4 + r));

    const int b = bh >> 4, h = bh & 15;
#pragma unroll
    for (int r = 0; r < 4; r++) {
        const int q = qt * 64 + w * 16 + quad * 4 + r;
        unsigned short* orow = O + ((size_t)b * SEQ + q) * D_MODEL + h * HEAD_DIM;
#pragma unroll
        for (int dt = 0; dt < 4; dt++)
            orow[dt * 16 + l15] = f2bf(o_acc[dt][r] * lr[r]);
    }
}

// ---------------------------------------------------------------------------
extern "C" void kernel_launch(void* const* d_in, const int* in_sizes, int n_in,
                              void* d_out, int out_size, void* d_ws, size_t ws_size,
                              hipStream_t stream) {
    const float* x      = (const float*)d_in[0];
    const float* w_qkv  = (const float*)d_in[1];
    const float* w_proj = (const float*)d_in[2];
    float* out = (float*)d_out;

    unsigned short* Xb  = (unsigned short*)d_ws;          // 4M
    unsigned short* Wqt = Xb  + (size_t)4 * 1024 * 1024;  // 3M
    unsigned short* Wpt = Wqt + (size_t)3 * 1024 * 1024;  // 1M
    unsigned short* Qb  = Wpt + (size_t)1 * 1024 * 1024;  // 4M
    unsigned short* Kb  = Qb  + (size_t)4 * 1024 * 1024;  // 4M
    unsigned short* Vtb = Kb  + (size_t)4 * 1024 * 1024;  // 4M
    unsigned short* Ob  = Vtb + (size_t)4 * 1024 * 1024;  // 4M

    convert_x_kernel<<<dim3(2048), 256, 0, stream>>>(x, Xb);
    convert_transpose_kernel<<<dim3(3072 / 32, 1024 / 32), 256, 0, stream>>>(
        w_qkv, Wqt, 3 * D_MODEL, D_MODEL);
    convert_transpose_kernel<<<dim3(1024 / 32, 1024 / 32), 256, 0, stream>>>(
        w_proj, Wpt, D_MODEL, D_MODEL);

    gemm_qkv_mfma<<<dim3(3 * D_MODEL / 128, BATCH * SEQ / 128), 256, 0, stream>>>(
        Xb, Wqt, Qb, Kb, Vtb);

    flash_attn_kernel<<<dim3(SEQ / 64 * BATCH * N_HEADS), 256, 0, stream>>>(
        Qb, Kb, Vtb, Ob);

    gemm_proj_mfma<<<dim3(D_MODEL / 128, BATCH * SEQ / 128), 256, 0, stream>>>(
        Ob, Wpt, out);
}

// Round 5
// 231.874 us; speedup vs baseline: 13.8562x; 1.0549x over previous
//
#include <hip/hip_runtime.h>
#include <cstdint>
#include <cstddef>

#define D_MODEL 1024
#define N_HEADS 16
#define HEAD_DIM 64
#define SEQ 2048
#define BATCH 2

typedef __attribute__((ext_vector_type(8))) short bf16x8;
typedef __attribute__((ext_vector_type(4))) float f32x4;

__device__ inline unsigned short f2bf(float f) {
    union { float f; unsigned u; } v; v.f = f;
    unsigned r = v.u + 0x7fffu + ((v.u >> 16) & 1u);
    return (unsigned short)(r >> 16);
}

// async global->LDS, 16 B per lane; LDS dst must be wave-base + lane*16.
__device__ __forceinline__ void gload_lds16(const unsigned short* g, unsigned short* l) {
    __builtin_amdgcn_global_load_lds(
        (const __attribute__((address_space(1))) unsigned int*)g,
        (__attribute__((address_space(3))) unsigned int*)l, 16, 0, 0);
}

// ---------------------------------------------------------------------------
// fp32 -> bf16 straight convert (x). 8 floats/thread.
// ---------------------------------------------------------------------------
__global__ __launch_bounds__(256) void convert_x_kernel(
    const float* __restrict__ X, unsigned short* __restrict__ Xb)
{
    const int idx = blockIdx.x * 256 + threadIdx.x;
    const float4* src = (const float4*)X;
    float4 v0 = src[idx * 2], v1 = src[idx * 2 + 1];
    union { unsigned short u[8]; uint4 v; } o;
    o.u[0] = f2bf(v0.x); o.u[1] = f2bf(v0.y); o.u[2] = f2bf(v0.z); o.u[3] = f2bf(v0.w);
    o.u[4] = f2bf(v1.x); o.u[5] = f2bf(v1.y); o.u[6] = f2bf(v1.z); o.u[7] = f2bf(v1.w);
    ((uint4*)Xb)[idx] = o.v;
}

// ---------------------------------------------------------------------------
// W[k][n] fp32 -> Wt[n][k] bf16, 32x32 LDS-tiled transpose.
// ---------------------------------------------------------------------------
__global__ __launch_bounds__(256) void convert_transpose_kernel(
    const float* __restrict__ W, unsigned short* __restrict__ Wt,
    int ncols, int nrows)
{
    __shared__ float t[32][33];
    const int c0 = blockIdx.x * 32, r0 = blockIdx.y * 32;
    const int a = threadIdx.x & 31, b = threadIdx.x >> 5;
#pragma unroll
    for (int i = 0; i < 32; i += 8)
        t[b + i][a] = W[(size_t)(r0 + b + i) * ncols + c0 + a];
    __syncthreads();
#pragma unroll
    for (int i = 0; i < 32; i += 8)
        Wt[(size_t)(c0 + b + i) * nrows + r0 + a] = f2bf(t[a][b + i]);
}

// ---------------------------------------------------------------------------
// bf16 MFMA GEMM core v2: 128x128 tile, BK=32, ASYNC DOUBLE-BUFFERED staging.
// One barrier per K-iter; prefetch of tile kt+1 issued right after the
// barrier and consumed at the next barrier (full compute phase in flight).
// LDS frag-order: frag f (m-tile) at [f*512 + lane*8]:
//   element A[row0 + f*16 + (lane&15)][k0 + (lane>>4)*8 .. +8]
// Wave w: rows (w>>1)*64, cols (w&1)*64; per iter 8 ds_read_b128 + 16 MFMA.
// LDS total 2*(8K+8K) = 32 KB.
// ---------------------------------------------------------------------------
#define GEMM_MFMA_BODY(A_, B_, Kdim)                                           \
    const int tid = threadIdx.x;                                               \
    const int w = tid >> 6, lane = tid & 63;                                   \
    const int l15 = lane & 15, quad = lane >> 4;                               \
    const int wr = w >> 1, wc = w & 1;                                         \
    const int row0 = blockIdx.y * 128, col0 = blockIdx.x * 128;                \
    __shared__ unsigned short As[2][4096];                                     \
    __shared__ unsigned short Bs[2][4096];                                     \
    const f32x4 zero4 = {0.f, 0.f, 0.f, 0.f};                                  \
    f32x4 acc[4][4];                                                           \
    _Pragma("unroll") for (int i = 0; i < 4; i++)                              \
        _Pragma("unroll") for (int j = 0; j < 4; j++) acc[i][j] = zero4;       \
    auto stage_ = [&](int sb, int k0) {                                        \
        _Pragma("unroll") for (int i = 0; i < 2; i++) {                        \
            const int f = w * 2 + i;                                           \
            gload_lds16((A_) + (size_t)(row0 + f * 16 + l15) * (Kdim) + k0 + quad * 8, \
                        &As[sb][f * 512 + lane * 8]);                          \
            gload_lds16((B_) + (size_t)(col0 + f * 16 + l15) * (Kdim) + k0 + quad * 8, \
                        &Bs[sb][f * 512 + lane * 8]);                          \
        }                                                                      \
    };                                                                         \
    stage_(0, 0);                                                              \
    const int KITER = (Kdim) / 32;                                             \
    for (int kt = 0; kt < KITER; kt++) {                                       \
        const int sb = kt & 1;                                                 \
        __syncthreads();                                                       \
        if (kt + 1 < KITER) stage_(sb ^ 1, (kt + 1) * 32);                     \
        bf16x8 af[4], bfr[4];                                                  \
        _Pragma("unroll") for (int i = 0; i < 4; i++)                          \
            af[i] = *(const bf16x8*)&As[sb][(wr * 4 + i) * 512 + lane * 8];    \
        _Pragma("unroll") for (int j = 0; j < 4; j++)                          \
            bfr[j] = *(const bf16x8*)&Bs[sb][(wc * 4 + j) * 512 + lane * 8];   \
        _Pragma("unroll") for (int i = 0; i < 4; i++)                          \
            _Pragma("unroll") for (int j = 0; j < 4; j++)                      \
                acc[i][j] = __builtin_amdgcn_mfma_f32_16x16x32_bf16(           \
                    af[i], bfr[j], acc[i][j], 0, 0, 0);                        \
    }

// GEMM1: Xb[4096][1024] @ Wqt[3072][1024]^T, scatter epilogue -> Q/K/Vt bf16.
__global__ __launch_bounds__(256) void gemm_qkv_mfma(
    const unsigned short* __restrict__ A, const unsigned short* __restrict__ B,
    unsigned short* __restrict__ Q, unsigned short* __restrict__ Kq,
    unsigned short* __restrict__ Vt)
{
    GEMM_MFMA_BODY(A, B, D_MODEL)
#pragma unroll
    for (int i = 0; i < 4; i++) {
#pragma unroll
        for (int r = 0; r < 4; r++) {
            const int row = row0 + wr * 64 + i * 16 + quad * 4 + r;
            const int bb = row >> 11, n = row & (SEQ - 1);
#pragma unroll
            for (int j = 0; j < 4; j++) {
                const int c = col0 + wc * 64 + j * 16 + l15;
                const int which = c % 3;
                const int dd = (c / 3) & (HEAD_DIM - 1);
                const int h = c / (3 * HEAD_DIM);
                const int bh = bb * N_HEADS + h;
                const unsigned short v = f2bf(acc[i][j][r]);
                if (which == 0)
                    Q[((size_t)bh * SEQ + n) * HEAD_DIM + dd] = v;
                else if (which == 1)
                    Kq[((size_t)bh * SEQ + n) * HEAD_DIM + dd] = v;
                else
                    Vt[((size_t)bh * HEAD_DIM + dd) * SEQ + n] = v;
            }
        }
    }
}

// GEMM2: Ob[4096][1024] @ Wpt[1024][1024]^T -> out fp32.
__global__ __launch_bounds__(256) void gemm_proj_mfma(
    const unsigned short* __restrict__ A, const unsigned short* __restrict__ B,
    float* __restrict__ C)
{
    GEMM_MFMA_BODY(A, B, D_MODEL)
#pragma unroll
    for (int i = 0; i < 4; i++) {
#pragma unroll
        for (int r = 0; r < 4; r++) {
            const int row = row0 + wr * 64 + i * 16 + quad * 4 + r;
#pragma unroll
            for (int j = 0; j < 4; j++) {
                const int c = col0 + wc * 64 + j * 16 + l15;
                C[(size_t)row * D_MODEL + c] = acc[i][j][r];
            }
        }
    }
}

// ---------------------------------------------------------------------------
// Flash attention v2 (unchanged from R4): S^T trick + register Q + async
// double-buffered K/V staging.
// ---------------------------------------------------------------------------
#define PSTR 72

__global__ __launch_bounds__(256) void flash_attn_kernel(
    const unsigned short* __restrict__ Q,
    const unsigned short* __restrict__ K,
    const unsigned short* __restrict__ Vt,
    unsigned short* __restrict__ O)
{
    const int idx = blockIdx.x;
    const int bh = idx & 31;
    const int qt2 = idx >> 5;
    const int hi = qt2 >> 3, lo = qt2 & 7;
    const int qt = (hi == 0) ? lo : (hi == 1) ? 31 - lo : (hi == 2) ? lo + 8 : 23 - lo;

    const int tid = threadIdx.x;
    const int w = tid >> 6, lane = tid & 63;
    const int l15 = lane & 15, quad = lane >> 4;

    __shared__ unsigned short Ks[2][4096];
    __shared__ unsigned short Vs[2][4096];
    __shared__ unsigned short Ps[4][16 * PSTR];

    bf16x8 qf[2];
    {
        const unsigned short* qrow =
            Q + ((size_t)bh * SEQ + qt * 64 + w * 16 + l15) * HEAD_DIM;
        qf[0] = *(const bf16x8*)(qrow + quad * 8);
        qf[1] = *(const bf16x8*)(qrow + 32 + quad * 8);
    }

    const f32x4 zero4 = {0.f, 0.f, 0.f, 0.f};
    f32x4 o_acc[4] = {zero4, zero4, zero4, zero4};
    float m_i = -1e30f, l_i = 0.f;

    auto stage = [&](int bf, int kt_t) {
        const int key0 = kt_t * 64;
#pragma unroll
        for (int i = 0; i < 2; i++) {
            const int f = w * 2 + i;
            const int ct = f >> 1, kh = f & 1;
            gload_lds16(K + ((size_t)bh * SEQ + key0 + ct * 16 + l15) * HEAD_DIM
                          + kh * 32 + quad * 8,
                        &Ks[bf][f * 512 + lane * 8]);
            gload_lds16(Vt + ((size_t)bh * HEAD_DIM + ct * 16 + l15) * SEQ
                           + key0 + kh * 32 + quad * 8,
                        &Vs[bf][f * 512 + lane * 8]);
        }
    };

    stage(0, 0);
    int buf = 0;

    const int qg = qt * 64 + w * 16 + l15;

    for (int kt = 0; kt <= qt; kt++) {
        __syncthreads();
        if (kt < qt) stage(buf ^ 1, kt + 1);

        f32x4 st[4] = {zero4, zero4, zero4, zero4};
#pragma unroll
        for (int kh = 0; kh < 2; kh++) {
#pragma unroll
            for (int ct = 0; ct < 4; ct++) {
                bf16x8 kf = *(const bf16x8*)&Ks[buf][(ct * 2 + kh) * 512 + lane * 8];
                st[ct] = __builtin_amdgcn_mfma_f32_16x16x32_bf16(kf, qf[kh], st[ct], 0, 0, 0);
            }
        }

        const bool diag = (kt == qt);
        float mt = -1e30f;
#pragma unroll
        for (int ct = 0; ct < 4; ct++) {
#pragma unroll
            for (int r = 0; r < 4; r++) {
                float v = st[ct][r] * 0.125f;
                const int kg = kt * 64 + ct * 16 + quad * 4 + r;
                if (diag && kg > qg) v = -1e30f;
                st[ct][r] = v;
                mt = fmaxf(mt, v);
            }
        }
        mt = fmaxf(mt, __shfl_xor(mt, 16));
        mt = fmaxf(mt, __shfl_xor(mt, 32));

        const float mn = fmaxf(m_i, mt);
        const float alpha = __expf(m_i - mn);
        m_i = mn;

        float ls = 0.f;
#pragma unroll
        for (int ct = 0; ct < 4; ct++) {
            union { unsigned short u[4]; uint2 v; } pk;
#pragma unroll
            for (int r = 0; r < 4; r++) {
                float p = __expf(st[ct][r] - mn);
                ls += p;
                pk.u[r] = f2bf(p);
            }
            *(uint2*)&Ps[w][l15 * PSTR + ct * 16 + quad * 4] = pk.v;
        }
        ls += __shfl_xor(ls, 16);
        ls += __shfl_xor(ls, 32);
        l_i = l_i * alpha + ls;

        float ar[4];
#pragma unroll
        for (int r = 0; r < 4; r++)
            ar[r] = __shfl(alpha, (lane & 48) | (quad * 4 + r));
#pragma unroll
        for (int dt = 0; dt < 4; dt++)
#pragma unroll
            for (int r = 0; r < 4; r++)
                o_acc[dt][r] *= ar[r];

#pragma unroll
        for (int kh = 0; kh < 2; kh++) {
            bf16x8 pa = *(const bf16x8*)&Ps[w][l15 * PSTR + kh * 32 + quad * 8];
#pragma unroll
            for (int dt = 0; dt < 4; dt++) {
                bf16x8 vf = *(const bf16x8*)&Vs[buf][(dt * 2 + kh) * 512 + lane * 8];
                o_acc[dt] = __builtin_amdgcn_mfma_f32_16x16x32_bf16(pa, vf, o_acc[dt], 0, 0, 0);
            }
        }
        buf ^= 1;
    }

    const float linv = 1.0f / l_i;
    float lr[4];
#pragma unroll
    for (int r = 0; r < 4; r++)
        lr[r] = __shfl(linv, (lane & 48) | (quad * 4 + r));

    const int b = bh >> 4, h = bh & 15;
#pragma unroll
    for (int r = 0; r < 4; r++) {
        const int q = qt * 64 + w * 16 + quad * 4 + r;
        unsigned short* orow = O + ((size_t)b * SEQ + q) * D_MODEL + h * HEAD_DIM;
#pragma unroll
        for (int dt = 0; dt < 4; dt++)
            orow[dt * 16 + l15] = f2bf(o_acc[dt][r] * lr[r]);
    }
}

// ---------------------------------------------------------------------------
extern "C" void kernel_launch(void* const* d_in, const int* in_sizes, int n_in,
                              void* d_out, int out_size, void* d_ws, size_t ws_size,
                              hipStream_t stream) {
    const float* x      = (const float*)d_in[0];
    const float* w_qkv  = (const float*)d_in[1];
    const float* w_proj = (const float*)d_in[2];
    float* out = (float*)d_out;

    unsigned short* Xb  = (unsigned short*)d_ws;          // 4M
    unsigned short* Wqt = Xb  + (size_t)4 * 1024 * 1024;  // 3M
    unsigned short* Wpt = Wqt + (size_t)3 * 1024 * 1024;  // 1M
    unsigned short* Qb  = Wpt + (size_t)1 * 1024 * 1024;  // 4M
    unsigned short* Kb  = Qb  + (size_t)4 * 1024 * 1024;  // 4M
    unsigned short* Vtb = Kb  + (size_t)4 * 1024 * 1024;  // 4M
    unsigned short* Ob  = Vtb + (size_t)4 * 1024 * 1024;  // 4M

    convert_x_kernel<<<dim3(2048), 256, 0, stream>>>(x, Xb);
    convert_transpose_kernel<<<dim3(3072 / 32, 1024 / 32), 256, 0, stream>>>(
        w_qkv, Wqt, 3 * D_MODEL, D_MODEL);
    convert_transpose_kernel<<<dim3(1024 / 32, 1024 / 32), 256, 0, stream>>>(
        w_proj, Wpt, D_MODEL, D_MODEL);

    gemm_qkv_mfma<<<dim3(3 * D_MODEL / 128, BATCH * SEQ / 128), 256, 0, stream>>>(
        Xb, Wqt, Qb, Kb, Vtb);

    flash_attn_kernel<<<dim3(SEQ / 64 * BATCH * N_HEADS), 256, 0, stream>>>(
        Qb, Kb, Vtb, Ob);

    gemm_proj_mfma<<<dim3(D_MODEL / 128, BATCH * SEQ / 128), 256, 0, stream>>>(
        Ob, Wpt, out);
}

// Round 6
// 229.358 us; speedup vs baseline: 14.0083x; 1.0110x over previous
//
#include <hip/hip_runtime.h>
#include <cstdint>
#include <cstddef>

#define D_MODEL 1024
#define N_HEADS 16
#define HEAD_DIM 64
#define SEQ 2048
#define BATCH 2

typedef __attribute__((ext_vector_type(8))) short bf16x8;
typedef __attribute__((ext_vector_type(4))) float f32x4;

__device__ inline unsigned short f2bf(float f) {
    union { float f; unsigned u; } v; v.f = f;
    unsigned r = v.u + 0x7fffu + ((v.u >> 16) & 1u);
    return (unsigned short)(r >> 16);
}

// async global->LDS, 16 B per lane; LDS dst must be wave-base + lane*16.
__device__ __forceinline__ void gload_lds16(const unsigned short* g, unsigned short* l) {
    __builtin_amdgcn_global_load_lds(
        (const __attribute__((address_space(1))) unsigned int*)g,
        (__attribute__((address_space(3))) unsigned int*)l, 16, 0, 0);
}

// ---------------------------------------------------------------------------
// fp32 -> bf16 straight convert (x). 8 floats/thread.
// ---------------------------------------------------------------------------
__global__ __launch_bounds__(256) void convert_x_kernel(
    const float* __restrict__ X, unsigned short* __restrict__ Xb)
{
    const int idx = blockIdx.x * 256 + threadIdx.x;
    const float4* src = (const float4*)X;
    float4 v0 = src[idx * 2], v1 = src[idx * 2 + 1];
    union { unsigned short u[8]; uint4 v; } o;
    o.u[0] = f2bf(v0.x); o.u[1] = f2bf(v0.y); o.u[2] = f2bf(v0.z); o.u[3] = f2bf(v0.w);
    o.u[4] = f2bf(v1.x); o.u[5] = f2bf(v1.y); o.u[6] = f2bf(v1.z); o.u[7] = f2bf(v1.w);
    ((uint4*)Xb)[idx] = o.v;
}

// ---------------------------------------------------------------------------
// w_qkv[k][c] fp32 -> Wqt[n'][k] bf16, PERMUTED: n' = (c%3)*1024 + c/3
// (= which*1024 + h*64 + d). GEMM1's N axis becomes [which][head][d], so the
// epilogue de-interleave is block-uniform and fully coalesced.
// ---------------------------------------------------------------------------
__global__ __launch_bounds__(256) void convert_transpose_qkv(
    const float* __restrict__ W, unsigned short* __restrict__ Wt)
{
    __shared__ float t[32][33];
    const int c0 = blockIdx.x * 32, r0 = blockIdx.y * 32;
    const int a = threadIdx.x & 31, b = threadIdx.x >> 5;
#pragma unroll
    for (int i = 0; i < 32; i += 8)
        t[b + i][a] = W[(size_t)(r0 + b + i) * (3 * D_MODEL) + c0 + a];
    __syncthreads();
#pragma unroll
    for (int i = 0; i < 32; i += 8) {
        const int c = c0 + b + i;
        const int np = (c % 3) * 1024 + c / 3;
        Wt[(size_t)np * D_MODEL + r0 + a] = f2bf(t[a][b + i]);
    }
}

// ---------------------------------------------------------------------------
// w_proj[k][n] fp32 -> Wpt[n][k] bf16, plain 32x32 LDS-tiled transpose.
// ---------------------------------------------------------------------------
__global__ __launch_bounds__(256) void convert_transpose_kernel(
    const float* __restrict__ W, unsigned short* __restrict__ Wt,
    int ncols, int nrows)
{
    __shared__ float t[32][33];
    const int c0 = blockIdx.x * 32, r0 = blockIdx.y * 32;
    const int a = threadIdx.x & 31, b = threadIdx.x >> 5;
#pragma unroll
    for (int i = 0; i < 32; i += 8)
        t[b + i][a] = W[(size_t)(r0 + b + i) * ncols + c0 + a];
    __syncthreads();
#pragma unroll
    for (int i = 0; i < 32; i += 8)
        Wt[(size_t)(c0 + b + i) * nrows + r0 + a] = f2bf(t[a][b + i]);
}

// ---------------------------------------------------------------------------
// V[bh][n][d] -> Vt[bh][d][n], 64x64 bf16 tiles through LDS.
// ---------------------------------------------------------------------------
__global__ __launch_bounds__(256) void v_transpose(
    const unsigned short* __restrict__ V, unsigned short* __restrict__ Vt)
{
    const int n0 = blockIdx.x * 64;
    const int bh = blockIdx.y;
    __shared__ unsigned short t[64 * 72];
    const int tid = threadIdx.x;
    const uint4* src = (const uint4*)(V + ((size_t)bh * SEQ + n0) * HEAD_DIM);
#pragma unroll
    for (int it = 0; it < 2; it++) {
        const int lin = tid + it * 256;
        const int row = lin >> 3, p = lin & 7;
        ((uint4*)t)[row * 9 + p] = src[lin];
    }
    __syncthreads();
#pragma unroll
    for (int it = 0; it < 2; it++) {
        const int lin = tid + it * 256;
        const int drow = lin >> 3, p = lin & 7;
        union { unsigned short u[8]; uint4 v; } o;
#pragma unroll
        for (int e = 0; e < 8; e++) o.u[e] = t[(p * 8 + e) * 72 + drow];
        ((uint4*)(Vt + ((size_t)bh * HEAD_DIM + drow) * SEQ + n0))[p] = o.v;
    }
}

// ---------------------------------------------------------------------------
// bf16 MFMA GEMM core v3: 128x128 tile, BK=64, async double-buffered staging.
// One barrier per K-iter; prefetch of tile kt+1 issued right after the
// barrier, consumed at the next barrier (a full 32-MFMA compute phase in
// flight). LDS 2*(16K+16K) = 64 KB -> 2 blocks/CU.
// Frag-order LDS: frag(mt 0..7, kh 0..1) at (mt*2+kh)*512 shorts; element for
// lane: row = mt*16 + (lane&15), k = k0 + kh*32 + (lane>>4)*8 (+0..7).
// ---------------------------------------------------------------------------
#define GEMM_MFMA_BODY(A_, B_, Kdim)                                           \
    const int tid = threadIdx.x;                                               \
    const int w = tid >> 6, lane = tid & 63;                                   \
    const int l15 = lane & 15, quad = lane >> 4;                               \
    const int wr = w >> 1, wc = w & 1;                                         \
    const int row0 = blockIdx.y * 128, col0 = blockIdx.x * 128;                \
    __shared__ unsigned short As[2][8192];                                     \
    __shared__ unsigned short Bs[2][8192];                                     \
    const f32x4 zero4 = {0.f, 0.f, 0.f, 0.f};                                  \
    f32x4 acc[4][4];                                                           \
    _Pragma("unroll") for (int i = 0; i < 4; i++)                              \
        _Pragma("unroll") for (int j = 0; j < 4; j++) acc[i][j] = zero4;       \
    auto stage_ = [&](int sb, int k0) {                                        \
        _Pragma("unroll") for (int i = 0; i < 4; i++) {                        \
            const int fa = w * 4 + i;                                          \
            const int mt = fa >> 1, kh = fa & 1;                               \
            const int kc = k0 + kh * 32 + quad * 8;                            \
            gload_lds16((A_) + (size_t)(row0 + mt * 16 + l15) * (Kdim) + kc,   \
                        &As[sb][fa * 512 + lane * 8]);                         \
            gload_lds16((B_) + (size_t)(col0 + mt * 16 + l15) * (Kdim) + kc,   \
                        &Bs[sb][fa * 512 + lane * 8]);                         \
        }                                                                      \
    };                                                                         \
    stage_(0, 0);                                                              \
    const int KITER = (Kdim) / 64;                                             \
    for (int kt = 0; kt < KITER; kt++) {                                       \
        const int sb = kt & 1;                                                 \
        __syncthreads();                                                       \
        if (kt + 1 < KITER) stage_(sb ^ 1, (kt + 1) * 64);                     \
        _Pragma("unroll") for (int kh = 0; kh < 2; kh++) {                     \
            bf16x8 af[4], bfr[4];                                              \
            _Pragma("unroll") for (int i = 0; i < 4; i++)                      \
                af[i] = *(const bf16x8*)&As[sb][((wr * 4 + i) * 2 + kh) * 512 + lane * 8]; \
            _Pragma("unroll") for (int j = 0; j < 4; j++)                      \
                bfr[j] = *(const bf16x8*)&Bs[sb][((wc * 4 + j) * 2 + kh) * 512 + lane * 8]; \
            _Pragma("unroll") for (int i = 0; i < 4; i++)                      \
                _Pragma("unroll") for (int j = 0; j < 4; j++)                  \
                    acc[i][j] = __builtin_amdgcn_mfma_f32_16x16x32_bf16(       \
                        af[i], bfr[j], acc[i][j], 0, 0, 0);                    \
        }                                                                      \
    }

// GEMM1: Xb[4096][1024] @ Wqt[3072 perm][1024]^T.
// Permuted N: n' = which*1024 + h*64 + d -> `which` is uniform per wave,
// stores are 16-lane stride-1 coalesced. V written untransposed [bh][n][d].
__global__ __launch_bounds__(256) void gemm_qkv_mfma(
    const unsigned short* __restrict__ A, const unsigned short* __restrict__ B,
    unsigned short* __restrict__ Q, unsigned short* __restrict__ Kq,
    unsigned short* __restrict__ Vb)
{
    GEMM_MFMA_BODY(A, B, D_MODEL)
    const int nbase = col0 + wc * 64;              // wave-uniform
    const int which = nbase >> 10;
    unsigned short* const dst = (which == 0) ? Q : (which == 1) ? Kq : Vb;
#pragma unroll
    for (int i = 0; i < 4; i++) {
#pragma unroll
        for (int r = 0; r < 4; r++) {
            const int row = row0 + wr * 64 + i * 16 + quad * 4 + r;
            const int bb = row >> 11, n = row & (SEQ - 1);
#pragma unroll
            for (int j = 0; j < 4; j++) {
                const int idx = (nbase + j * 16 + l15) & 1023;  // h*64+d
                const int h = idx >> 6, dd = idx & 63;
                dst[(((size_t)(bb * N_HEADS + h)) * SEQ + n) * HEAD_DIM + dd] =
                    f2bf(acc[i][j][r]);
            }
        }
    }
}

// GEMM2: Ob[4096][1024] @ Wpt[1024][1024]^T -> out fp32.
__global__ __launch_bounds__(256) void gemm_proj_mfma(
    const unsigned short* __restrict__ A, const unsigned short* __restrict__ B,
    float* __restrict__ C)
{
    GEMM_MFMA_BODY(A, B, D_MODEL)
#pragma unroll
    for (int i = 0; i < 4; i++) {
#pragma unroll
        for (int r = 0; r < 4; r++) {
            const int row = row0 + wr * 64 + i * 16 + quad * 4 + r;
#pragma unroll
            for (int j = 0; j < 4; j++) {
                const int c = col0 + wc * 64 + j * 16 + l15;
                C[(size_t)row * D_MODEL + c] = acc[i][j][r];
            }
        }
    }
}

// ---------------------------------------------------------------------------
// Flash attention (unchanged from R4/R5): S^T trick + register Q + async
// double-buffered K/V staging.
// ---------------------------------------------------------------------------
#define PSTR 72

__global__ __launch_bounds__(256) void flash_attn_kernel(
    const unsigned short* __restrict__ Q,
    const unsigned short* __restrict__ K,
    const unsigned short* __restrict__ Vt,
    unsigned short* __restrict__ O)
{
    const int idx = blockIdx.x;
    const int bh = idx & 31;
    const int qt2 = idx >> 5;
    const int hi = qt2 >> 3, lo = qt2 & 7;
    const int qt = (hi == 0) ? lo : (hi == 1) ? 31 - lo : (hi == 2) ? lo + 8 : 23 - lo;

    const int tid = threadIdx.x;
    const int w = tid >> 6, lane = tid & 63;
    const int l15 = lane & 15, quad = lane >> 4;

    __shared__ unsigned short Ks[2][4096];
    __shared__ unsigned short Vs[2][4096];
    __shared__ unsigned short Ps[4][16 * PSTR];

    bf16x8 qf[2];
    {
        const unsigned short* qrow =
            Q + ((size_t)bh * SEQ + qt * 64 + w * 16 + l15) * HEAD_DIM;
        qf[0] = *(const bf16x8*)(qrow + quad * 8);
        qf[1] = *(const bf16x8*)(qrow + 32 + quad * 8);
    }

    const f32x4 zero4 = {0.f, 0.f, 0.f, 0.f};
    f32x4 o_acc[4] = {zero4, zero4, zero4, zero4};
    float m_i = -1e30f, l_i = 0.f;

    auto stage = [&](int bf, int kt_t) {
        const int key0 = kt_t * 64;
#pragma unroll
        for (int i = 0; i < 2; i++) {
            const int f = w * 2 + i;
            const int ct = f >> 1, kh = f & 1;
            gload_lds16(K + ((size_t)bh * SEQ + key0 + ct * 16 + l15) * HEAD_DIM
                          + kh * 32 + quad * 8,
                        &Ks[bf][f * 512 + lane * 8]);
            gload_lds16(Vt + ((size_t)bh * HEAD_DIM + ct * 16 + l15) * SEQ
                           + key0 + kh * 32 + quad * 8,
                        &Vs[bf][f * 512 + lane * 8]);
        }
    };

    stage(0, 0);
    int buf = 0;

    const int qg = qt * 64 + w * 16 + l15;

    for (int kt = 0; kt <= qt; kt++) {
        __syncthreads();
        if (kt < qt) stage(buf ^ 1, kt + 1);

        f32x4 st[4] = {zero4, zero4, zero4, zero4};
#pragma unroll
        for (int kh = 0; kh < 2; kh++) {
#pragma unroll
            for (int ct = 0; ct < 4; ct++) {
                bf16x8 kf = *(const bf16x8*)&Ks[buf][(ct * 2 + kh) * 512 + lane * 8];
                st[ct] = __builtin_amdgcn_mfma_f32_16x16x32_bf16(kf, qf[kh], st[ct], 0, 0, 0);
            }
        }

        const bool diag = (kt == qt);
        float mt = -1e30f;
#pragma unroll
        for (int ct = 0; ct < 4; ct++) {
#pragma unroll
            for (int r = 0; r < 4; r++) {
                float v = st[ct][r] * 0.125f;
                const int kg = kt * 64 + ct * 16 + quad * 4 + r;
                if (diag && kg > qg) v = -1e30f;
                st[ct][r] = v;
                mt = fmaxf(mt, v);
            }
        }
        mt = fmaxf(mt, __shfl_xor(mt, 16));
        mt = fmaxf(mt, __shfl_xor(mt, 32));

        const float mn = fmaxf(m_i, mt);
        const float alpha = __expf(m_i - mn);
        m_i = mn;

        float ls = 0.f;
#pragma unroll
        for (int ct = 0; ct < 4; ct++) {
            union { unsigned short u[4]; uint2 v; } pk;
#pragma unroll
            for (int r = 0; r < 4; r++) {
                float p = __expf(st[ct][r] - mn);
                ls += p;
                pk.u[r] = f2bf(p);
            }
            *(uint2*)&Ps[w][l15 * PSTR + ct * 16 + quad * 4] = pk.v;
        }
        ls += __shfl_xor(ls, 16);
        ls += __shfl_xor(ls, 32);
        l_i = l_i * alpha + ls;

        float ar[4];
#pragma unroll
        for (int r = 0; r < 4; r++)
            ar[r] = __shfl(alpha, (lane & 48) | (quad * 4 + r));
#pragma unroll
        for (int dt = 0; dt < 4; dt++)
#pragma unroll
            for (int r = 0; r < 4; r++)
                o_acc[dt][r] *= ar[r];

#pragma unroll
        for (int kh = 0; kh < 2; kh++) {
            bf16x8 pa = *(const bf16x8*)&Ps[w][l15 * PSTR + kh * 32 + quad * 8];
#pragma unroll
            for (int dt = 0; dt < 4; dt++) {
                bf16x8 vf = *(const bf16x8*)&Vs[buf][(dt * 2 + kh) * 512 + lane * 8];
                o_acc[dt] = __builtin_amdgcn_mfma_f32_16x16x32_bf16(pa, vf, o_acc[dt], 0, 0, 0);
            }
        }
        buf ^= 1;
    }

    const float linv = 1.0f / l_i;
    float lr[4];
#pragma unroll
    for (int r = 0; r < 4; r++)
        lr[r] = __shfl(linv, (lane & 48) | (quad * 4 + r));

    const int b = bh >> 4, h = bh & 15;
#pragma unroll
    for (int r = 0; r < 4; r++) {
        const int q = qt * 64 + w * 16 + quad * 4 + r;
        unsigned short* orow = O + ((size_t)b * SEQ + q) * D_MODEL + h * HEAD_DIM;
#pragma unroll
        for (int dt = 0; dt < 4; dt++)
            orow[dt * 16 + l15] = f2bf(o_acc[dt][r] * lr[r]);
    }
}

// ---------------------------------------------------------------------------
extern "C" void kernel_launch(void* const* d_in, const int* in_sizes, int n_in,
                              void* d_out, int out_size, void* d_ws, size_t ws_size,
                              hipStream_t stream) {
    const float* x      = (const float*)d_in[0];
    const float* w_qkv  = (const float*)d_in[1];
    const float* w_proj = (const float*)d_in[2];
    float* out = (float*)d_out;

    unsigned short* Xb  = (unsigned short*)d_ws;          // 4M shorts
    unsigned short* Wqt = Xb  + (size_t)4 * 1024 * 1024;  // 3M
    unsigned short* Wpt = Wqt + (size_t)3 * 1024 * 1024;  // 1M
    unsigned short* Qb  = Wpt + (size_t)1 * 1024 * 1024;  // 4M
    unsigned short* Kb  = Qb  + (size_t)4 * 1024 * 1024;  // 4M
    unsigned short* Vb  = Kb  + (size_t)4 * 1024 * 1024;  // 4M (untransposed)
    unsigned short* Vtb = Vb  + (size_t)4 * 1024 * 1024;  // 4M
    unsigned short* Ob  = Vtb + (size_t)4 * 1024 * 1024;  // 4M  (56 MB total)

    convert_x_kernel<<<dim3(2048), 256, 0, stream>>>(x, Xb);
    convert_transpose_qkv<<<dim3(3072 / 32, 1024 / 32), 256, 0, stream>>>(w_qkv, Wqt);
    convert_transpose_kernel<<<dim3(1024 / 32, 1024 / 32), 256, 0, stream>>>(
        w_proj, Wpt, D_MODEL, D_MODEL);

    gemm_qkv_mfma<<<dim3(3 * D_MODEL / 128, BATCH * SEQ / 128), 256, 0, stream>>>(
        Xb, Wqt, Qb, Kb, Vb);

    v_transpose<<<dim3(SEQ / 64, BATCH * N_HEADS), 256, 0, stream>>>(Vb, Vtb);

    flash_attn_kernel<<<dim3(SEQ / 64 * BATCH * N_HEADS), 256, 0, stream>>>(
        Qb, Kb, Vtb, Ob);

    gemm_proj_mfma<<<dim3(D_MODEL / 128, BATCH * SEQ / 128), 256, 0, stream>>>(
        Ob, Wpt, out);
}